// Round 7
// baseline (297.741 us; speedup 1.0000x reference)
//
#include <hip/hip_runtime.h>

#define H 4
#define D1 128
#define D2 256
#define CIN 16
#define SLOPE 0.2f
#define LOG2E 1.4426950408889634f

typedef short short8v __attribute__((ext_vector_type(8)));
typedef float float4v __attribute__((ext_vector_type(4)));

__device__ __forceinline__ float bflo(unsigned u) { return __uint_as_float(u << 16); }
__device__ __forceinline__ float bfhi(unsigned u) { return __uint_as_float(u & 0xFFFF0000u); }
__device__ __forceinline__ unsigned short f2bf(float f) {
    unsigned int u = __float_as_uint(f);
    u += 0x7FFFu + ((u >> 16) & 1u);
    return (unsigned short)(u >> 16);
}

// ============ CSR build ============
__global__ void k_hist(const int* __restrict__ ei, int E, int ET,
                       int* __restrict__ deg) {
    int idx = blockIdx.x * blockDim.x + threadIdx.x;
    if (idx >= ET) return;
    int dst = (idx < E) ? ei[E + idx] : idx - E;
    atomicAdd(&deg[dst], 1);
}

__global__ __launch_bounds__(1024) void k_scan_one(
        const int* __restrict__ deg, int* __restrict__ rp,
        int* __restrict__ cur, int n) {
    __shared__ int wsum[16];
    int t = threadIdx.x;
    int lane = t & 63, w = t >> 6;
    int base = t * 32;
    int loc[32];
    int s = 0;
#pragma unroll
    for (int k = 0; k < 32; ++k) {
        int idx = base + k;
        int v = (idx < n) ? deg[idx] : 0;
        loc[k] = s;
        s += v;
    }
    int inc = s;
#pragma unroll
    for (int off = 1; off < 64; off <<= 1) {
        int u = __shfl_up(inc, off, 64);
        if (lane >= off) inc += u;
    }
    int excl = inc - s;
    if (lane == 63) wsum[w] = inc;
    __syncthreads();
    if (w == 0) {
        int v = (lane < 16) ? wsum[lane] : 0;
        int winc = v;
#pragma unroll
        for (int off = 1; off < 16; off <<= 1) {
            int u = __shfl_up(winc, off, 64);
            if (lane >= off) winc += u;
        }
        if (lane < 16) wsum[lane] = winc - v;
    }
    __syncthreads();
    int offw = wsum[w] + excl;
#pragma unroll
    for (int k = 0; k < 32; ++k) {
        int idx = base + k;
        if (idx < n) { rp[idx] = offw + loc[k]; cur[idx] = 0; }
    }
}

__global__ void k_fill(const int* __restrict__ ei, int E, int ET,
                       const int* __restrict__ rp, int* __restrict__ cur,
                       int* __restrict__ eord) {
    int idx = blockIdx.x * blockDim.x + threadIdx.x;
    if (idx >= ET) return;
    int src, dst;
    if (idx < E) { src = ei[idx]; dst = ei[E + idx]; }
    else         { src = dst = idx - E; }
    int pos = atomicAdd(&cur[dst], 1);
    eord[rp[dst] + pos] = src;
}

// ============ W2 convert+transpose: fp32 -> [512][128] bf16 ============
__global__ __launch_bounds__(256) void k_cvtW2(
        const float* __restrict__ Wl, const float* __restrict__ Wr,
        unsigned short* __restrict__ W2t) {
    int idx = blockIdx.x * 256 + threadIdx.x;   // 0..65535
    int k = idx >> 9, c = idx & 511;
    float v = (c < 256) ? Wl[k * 256 + c] : Wr[k * 256 + (c - 256)];
    W2t[(size_t)c * 128 + k] = f2bf(v);
}

// ============ layer-1 linear: head-split bf16 outputs [H][n][32] ============
__global__ __launch_bounds__(256) void k_lin1(
        const float* __restrict__ x, const float* __restrict__ lb,
        const float* __restrict__ ub,
        const float* __restrict__ Wl, const float* __restrict__ bl,
        const float* __restrict__ Wr, const float* __restrict__ br,
        unsigned short* __restrict__ xl1h, unsigned short* __restrict__ xr1h,
        int n) {
    __shared__ float Wls[CIN][D1];
    __shared__ float Wrs[CIN][D1];
    __shared__ float ys[16][CIN];
    int t = threadIdx.x;
    int i0 = blockIdx.x * 16;
#pragma unroll
    for (int i = 0; i < 8; ++i) {
        int flat = t + 256 * i;
        int k = flat >> 7, c = flat & 127;
        Wls[k][c] = Wl[k * D1 + c];
        Wrs[k][c] = Wr[k * D1 + c];
    }
    {
        int node = t >> 4, k = t & 15;
        int gi = i0 + node;
        float xv = (gi < n) ? x[(size_t)gi * CIN + k] : 0.f;
        ys[node][k] = (xv - lb[k]) / (ub[k] - lb[k]);
    }
    __syncthreads();
    int c = t & 127;
    bool left = t < 128;
    const float (*Ws)[D1] = left ? Wls : Wrs;
    float bias = left ? bl[c] : br[c];
    int hh = c >> 5, cc = c & 31;
    for (int j = 0; j < 16; ++j) {
        float acc = bias;
#pragma unroll
        for (int k = 0; k < CIN; ++k) acc += ys[j][k] * Ws[k][c];
        int gi = i0 + j;
        if (gi < n) {
            size_t addr = ((size_t)hh * n + gi) * 32 + cc;
            if (left) xl1h[addr] = f2bf(acc);
            else      xr1h[addr] = f2bf(acc);
        }
    }
}

// ============ layer-2 linear: bf16 MFMA GEMM, head-split outputs ============
__global__ __launch_bounds__(256) void k_lin2_mfma(
        const unsigned short* __restrict__ h1b,   // [n][128] bf16
        const unsigned short* __restrict__ W2t,   // [512][128] bf16
        const float* __restrict__ b2l, const float* __restrict__ b2r,
        unsigned short* __restrict__ xl2h,        // [4][n][64] bf16
        unsigned short* __restrict__ xr2h,        // [4][n][64] bf16
        int n) {
    __shared__ unsigned short At[128 * 128];
    __shared__ unsigned short Bt[128 * 128];
    int t = threadIdx.x;
    int row0 = blockIdx.x * 128;
    int col0 = blockIdx.y * 128;

    {
        int r = t >> 1, hh = (t & 1) * 64;
        bool ok = (row0 + r) < n;
        const unsigned short* gA = h1b + (size_t)(row0 + r) * 128 + hh;
        const unsigned short* gB = W2t + (size_t)(col0 + r) * 128 + hh;
#pragma unroll
        for (int i = 0; i < 8; ++i) {
            uint4 vA = ok ? *(const uint4*)(gA + i * 8) : make_uint4(0, 0, 0, 0);
            uint4 vB = *(const uint4*)(gB + i * 8);
            int col = hh + i * 8;
            int idx = (r * 128 + col) ^ ((r & 15) << 3);
            *(uint4*)&At[idx] = vA;
            *(uint4*)&Bt[idx] = vB;
        }
    }
    __syncthreads();

    int w = t >> 6, l = t & 63;
    int wr = w >> 1, wc = w & 1;
    float4v acc[4][4];
#pragma unroll
    for (int m = 0; m < 4; ++m)
#pragma unroll
        for (int nn = 0; nn < 4; ++nn) acc[m][nn] = (float4v)0.f;

#pragma unroll
    for (int ks = 0; ks < 4; ++ks) {
        int kb = ks * 32 + ((l >> 4) << 3);
        short8v a[4], b[4];
#pragma unroll
        for (int m = 0; m < 4; ++m) {
            int r = wr * 64 + m * 16 + (l & 15);
            a[m] = *(const short8v*)&At[(r * 128 + kb) ^ ((r & 15) << 3)];
        }
#pragma unroll
        for (int nn = 0; nn < 4; ++nn) {
            int c = wc * 64 + nn * 16 + (l & 15);
            b[nn] = *(const short8v*)&Bt[(c * 128 + kb) ^ ((c & 15) << 3)];
        }
#pragma unroll
        for (int m = 0; m < 4; ++m)
#pragma unroll
            for (int nn = 0; nn < 4; ++nn)
                acc[m][nn] = __builtin_amdgcn_mfma_f32_16x16x32_bf16(
                    a[m], b[nn], acc[m][nn], 0, 0, 0);
    }

    unsigned short* ob = (col0 < 256) ? xl2h : xr2h;
    const float* bp = (col0 < 256) ? b2l : b2r;
    int cb = (col0 < 256) ? col0 : col0 - 256;
#pragma unroll
    for (int nn = 0; nn < 4; ++nn) {
        int colc = cb + wc * 64 + nn * 16 + (l & 15);
        float bv = bp[colc];
        size_t hbase = (size_t)(colc >> 6) * n;
        int ccc = colc & 63;
#pragma unroll
        for (int m = 0; m < 4; ++m) {
            int rbase = row0 + wr * 64 + m * 16 + ((l >> 4) << 2);
#pragma unroll
            for (int r = 0; r < 4; ++r) {
                int row = rbase + r;
                if (row < n)
                    ob[(hbase + row) * 64 + ccc] = f2bf(acc[m][nn][r] + bv);
            }
        }
    }
}

// ============ layer-1 aggregation, head-split ============
// block 256 = 4 waves; wave = 1 (node, head); 8 groups x 8 lanes = 8 edges/iter.
// XCD pinning: head = (blockIdx&7)>>1 (2 XCDs per head; table 1.9 MB < 4 MB L2)
__global__ __launch_bounds__(256) void k_agg1h(
        const unsigned short* __restrict__ xl,   // [4][n][32] bf16
        const unsigned short* __restrict__ xr,   // [4][n][32] bf16
        const float* __restrict__ att,           // [4][32]
        const float* __restrict__ bias,          // [128]
        const int* __restrict__ rp, const int* __restrict__ deg,
        const int* __restrict__ eord,
        unsigned short* __restrict__ h1b,        // [n][128] bf16 (concat)
        int n) {
    int t = threadIdx.x;
    int b = blockIdx.x;
    int head = (b & 7) >> 1;
    int sub = ((b >> 3) << 1) | (b & 1);
    int node = sub * 4 + (t >> 6);
    int l = t & 63, g = l >> 3, p = l & 7;
    int nd = (node < n) ? node : n - 1;
    size_t hb = (size_t)head * n;
    const uint2* xlp = (const uint2*)xl;   // row = 8 uint2
    const uint2* xrp = (const uint2*)xr;
    uint2 xru = xrp[(hb + nd) * 8 + p];
    float4 xrv = make_float4(bflo(xru.x), bfhi(xru.x), bflo(xru.y), bfhi(xru.y));
    float4 av  = *(const float4*)(att + head * 32 + 4 * p);
    av.x *= LOG2E; av.y *= LOG2E; av.z *= LOG2E; av.w *= LOG2E;
    int start = __builtin_amdgcn_readfirstlane(rp[nd]);
    int cnt   = (node < n) ? deg[nd] : 0;
    cnt = __builtin_amdgcn_readfirstlane(cnt);
    float d = 0.f, a0 = 0.f, a1 = 0.f, a2 = 0.f, a3 = 0.f;
    if (cnt > 0) {
        int T = (cnt + 7) >> 3;
        int ecl = cnt - 1;
        uint2 r;
        {
            int jj = g; if (jj > ecl) jj = ecl;
            r = xlp[(hb + eord[start + jj]) * 8 + p];
        }
        for (int it = 0; it < T - 1; ++it) {
            uint2 cur = r;
            {
                int jj = (it + 1) * 8 + g; if (jj > ecl) jj = ecl;
                r = xlp[(hb + eord[start + jj]) * 8 + p];
            }
            float x0 = bflo(cur.x), x1 = bfhi(cur.x), x2 = bflo(cur.y), x3 = bfhi(cur.y);
            float v, lg;
            v = x0 + xrv.x; v = fmaxf(v, SLOPE * v); lg  = av.x * v;
            v = x1 + xrv.y; v = fmaxf(v, SLOPE * v); lg += av.y * v;
            v = x2 + xrv.z; v = fmaxf(v, SLOPE * v); lg += av.z * v;
            v = x3 + xrv.w; v = fmaxf(v, SLOPE * v); lg += av.w * v;
            lg += __shfl_xor(lg, 4);
            lg += __shfl_xor(lg, 2);
            lg += __shfl_xor(lg, 1);
            float e = exp2f(lg);
            d += e;
            a0 += e * x0; a1 += e * x1; a2 += e * x2; a3 += e * x3;
        }
        {   // final (possibly partial) iteration
            uint2 cur = r;
            int j = (T - 1) * 8;
            float x0 = bflo(cur.x), x1 = bfhi(cur.x), x2 = bflo(cur.y), x3 = bfhi(cur.y);
            float v, lg;
            v = x0 + xrv.x; v = fmaxf(v, SLOPE * v); lg  = av.x * v;
            v = x1 + xrv.y; v = fmaxf(v, SLOPE * v); lg += av.y * v;
            v = x2 + xrv.z; v = fmaxf(v, SLOPE * v); lg += av.z * v;
            v = x3 + xrv.w; v = fmaxf(v, SLOPE * v); lg += av.w * v;
            lg += __shfl_xor(lg, 4);
            lg += __shfl_xor(lg, 2);
            lg += __shfl_xor(lg, 1);
            float e = (j + g <= ecl) ? exp2f(lg) : 0.f;
            d += e;
            a0 += e * x0; a1 += e * x1; a2 += e * x2; a3 += e * x3;
        }
    }
    // cross-group reduce (8 -> 1)
    d += __shfl_xor(d, 8);  a0 += __shfl_xor(a0, 8);  a1 += __shfl_xor(a1, 8);
    a2 += __shfl_xor(a2, 8);  a3 += __shfl_xor(a3, 8);
    d += __shfl_xor(d, 16); a0 += __shfl_xor(a0, 16); a1 += __shfl_xor(a1, 16);
    a2 += __shfl_xor(a2, 16); a3 += __shfl_xor(a3, 16);
    d += __shfl_xor(d, 32); a0 += __shfl_xor(a0, 32); a1 += __shfl_xor(a1, 32);
    a2 += __shfl_xor(a2, 32); a3 += __shfl_xor(a3, 32);
    if (l < 8 && node < n) {
        float inv = 1.f / d;
        float4 bv = *(const float4*)(bias + head * 32 + 4 * p);
        float o0 = fmaxf(a0 * inv + bv.x, 0.f);
        float o1 = fmaxf(a1 * inv + bv.y, 0.f);
        float o2 = fmaxf(a2 * inv + bv.z, 0.f);
        float o3 = fmaxf(a3 * inv + bv.w, 0.f);
        uint2 o;
        o.x = ((unsigned)f2bf(o1) << 16) | f2bf(o0);
        o.y = ((unsigned)f2bf(o3) << 16) | f2bf(o2);
        ((uint2*)h1b)[(size_t)node * 32 + head * 8 + p] = o;
    }
}

// ============ layer-2 aggregation, head-split ============
// wave = 1 (node, head); 4 groups x 16 lanes = 4 edges/iter; table 3.8 MB/head.
__global__ __launch_bounds__(256) void k_agg2h(
        const unsigned short* __restrict__ xl,   // [4][n][64] bf16
        const unsigned short* __restrict__ xr,   // [4][n][64] bf16
        const float* __restrict__ att,           // [4][64]
        const int* __restrict__ rp, const int* __restrict__ deg,
        const int* __restrict__ eord,
        unsigned short* __restrict__ o2h,        // [4][n][64] bf16
        int n) {
    int t = threadIdx.x;
    int b = blockIdx.x;
    int head = (b & 7) >> 1;
    int sub = ((b >> 3) << 1) | (b & 1);
    int node = sub * 4 + (t >> 6);
    int l = t & 63, g = l >> 4, p = l & 15;
    int nd = (node < n) ? node : n - 1;
    size_t hb = (size_t)head * n;
    const uint2* xlp = (const uint2*)xl;   // row = 16 uint2
    const uint2* xrp = (const uint2*)xr;
    uint2 xru = xrp[(hb + nd) * 16 + p];
    float4 xrv = make_float4(bflo(xru.x), bfhi(xru.x), bflo(xru.y), bfhi(xru.y));
    float4 av  = *(const float4*)(att + head * 64 + 4 * p);
    av.x *= LOG2E; av.y *= LOG2E; av.z *= LOG2E; av.w *= LOG2E;
    int start = __builtin_amdgcn_readfirstlane(rp[nd]);
    int cnt   = (node < n) ? deg[nd] : 0;
    cnt = __builtin_amdgcn_readfirstlane(cnt);
    float d = 0.f, a0 = 0.f, a1 = 0.f, a2 = 0.f, a3 = 0.f;
    if (cnt > 0) {
        int T = (cnt + 3) >> 2;
        int ecl = cnt - 1;
        uint2 r;
        {
            int jj = g; if (jj > ecl) jj = ecl;
            r = xlp[(hb + eord[start + jj]) * 16 + p];
        }
        for (int it = 0; it < T - 1; ++it) {
            uint2 cur = r;
            {
                int jj = (it + 1) * 4 + g; if (jj > ecl) jj = ecl;
                r = xlp[(hb + eord[start + jj]) * 16 + p];
            }
            float x0 = bflo(cur.x), x1 = bfhi(cur.x), x2 = bflo(cur.y), x3 = bfhi(cur.y);
            float v, lg;
            v = x0 + xrv.x; v = fmaxf(v, SLOPE * v); lg  = av.x * v;
            v = x1 + xrv.y; v = fmaxf(v, SLOPE * v); lg += av.y * v;
            v = x2 + xrv.z; v = fmaxf(v, SLOPE * v); lg += av.z * v;
            v = x3 + xrv.w; v = fmaxf(v, SLOPE * v); lg += av.w * v;
            lg += __shfl_xor(lg, 8);
            lg += __shfl_xor(lg, 4);
            lg += __shfl_xor(lg, 2);
            lg += __shfl_xor(lg, 1);
            float e = exp2f(lg);
            d += e;
            a0 += e * x0; a1 += e * x1; a2 += e * x2; a3 += e * x3;
        }
        {
            uint2 cur = r;
            int j = (T - 1) * 4;
            float x0 = bflo(cur.x), x1 = bfhi(cur.x), x2 = bflo(cur.y), x3 = bfhi(cur.y);
            float v, lg;
            v = x0 + xrv.x; v = fmaxf(v, SLOPE * v); lg  = av.x * v;
            v = x1 + xrv.y; v = fmaxf(v, SLOPE * v); lg += av.y * v;
            v = x2 + xrv.z; v = fmaxf(v, SLOPE * v); lg += av.z * v;
            v = x3 + xrv.w; v = fmaxf(v, SLOPE * v); lg += av.w * v;
            lg += __shfl_xor(lg, 8);
            lg += __shfl_xor(lg, 4);
            lg += __shfl_xor(lg, 2);
            lg += __shfl_xor(lg, 1);
            float e = (j + g <= ecl) ? exp2f(lg) : 0.f;
            d += e;
            a0 += e * x0; a1 += e * x1; a2 += e * x2; a3 += e * x3;
        }
    }
    // cross-group reduce (4 -> 1)
    d += __shfl_xor(d, 16); a0 += __shfl_xor(a0, 16); a1 += __shfl_xor(a1, 16);
    a2 += __shfl_xor(a2, 16); a3 += __shfl_xor(a3, 16);
    d += __shfl_xor(d, 32); a0 += __shfl_xor(a0, 32); a1 += __shfl_xor(a1, 32);
    a2 += __shfl_xor(a2, 32); a3 += __shfl_xor(a3, 32);
    if (l < 16 && node < n) {
        float inv = 1.f / d;
        uint2 o;
        o.x = ((unsigned)f2bf(a1 * inv) << 16) | f2bf(a0 * inv);
        o.y = ((unsigned)f2bf(a3 * inv) << 16) | f2bf(a2 * inv);
        ((uint2*)o2h)[(hb + node) * 16 + p] = o;
    }
}

// ============ final: mean heads + bias2 + relu + W3 + sigmoid ============
// 256 thr = 16 nodes x 16 lanes.
__global__ __launch_bounds__(256) void k_fin2(
        const unsigned short* __restrict__ o2h,  // [4][n][64] bf16
        const float* __restrict__ b2,
        const float* __restrict__ W3, const float* __restrict__ b3,
        float* __restrict__ out, int n) {
    int t = threadIdx.x;
    int node = blockIdx.x * 16 + (t >> 4);
    int p = t & 15;
    int nd = (node < n) ? node : n - 1;
    const uint2* op = (const uint2*)o2h;
    float s0 = 0.f, s1 = 0.f, s2 = 0.f, s3 = 0.f;
#pragma unroll
    for (int h = 0; h < H; ++h) {
        uint2 u = op[((size_t)h * n + nd) * 16 + p];
        s0 += bflo(u.x); s1 += bfhi(u.x); s2 += bflo(u.y); s3 += bfhi(u.y);
    }
    int c0 = 4 * p;
    float4 bv = *(const float4*)(b2 + c0);
    float v0 = fmaxf(0.25f * s0 + bv.x, 0.f);
    float v1 = fmaxf(0.25f * s1 + bv.y, 0.f);
    float v2 = fmaxf(0.25f * s2 + bv.z, 0.f);
    float v3 = fmaxf(0.25f * s3 + bv.w, 0.f);
    float p0, p1, p2, p3, p4;
    {
        const float* w0 = W3 + (c0 + 0) * 5;
        const float* w1 = W3 + (c0 + 1) * 5;
        const float* w2 = W3 + (c0 + 2) * 5;
        const float* w3 = W3 + (c0 + 3) * 5;
        p0 = v0 * w0[0] + v1 * w1[0] + v2 * w2[0] + v3 * w3[0];
        p1 = v0 * w0[1] + v1 * w1[1] + v2 * w2[1] + v3 * w3[1];
        p2 = v0 * w0[2] + v1 * w1[2] + v2 * w2[2] + v3 * w3[2];
        p3 = v0 * w0[3] + v1 * w1[3] + v2 * w2[3] + v3 * w3[3];
        p4 = v0 * w0[4] + v1 * w1[4] + v2 * w2[4] + v3 * w3[4];
    }
#pragma unroll
    for (int off = 1; off < 16; off <<= 1) {
        p0 += __shfl_xor(p0, off); p1 += __shfl_xor(p1, off);
        p2 += __shfl_xor(p2, off); p3 += __shfl_xor(p3, off);
        p4 += __shfl_xor(p4, off);
    }
    if (p == 0 && node < n) {
        float* o = out + (size_t)node * 5;
        o[0] = 1.f / (1.f + __expf(-(p0 + b3[0])));
        o[1] = 1.f / (1.f + __expf(-(p1 + b3[1])));
        o[2] = 1.f / (1.f + __expf(-(p2 + b3[2])));
        o[3] = 1.f / (1.f + __expf(-(p3 + b3[3])));
        o[4] = 1.f / (1.f + __expf(-(p4 + b3[4])));
    }
}

extern "C" void kernel_launch(void* const* d_in, const int* in_sizes, int n_in,
                              void* d_out, int out_size, void* d_ws, size_t ws_size,
                              hipStream_t stream) {
    const float* x     = (const float*)d_in[0];
    const int*   ei    = (const int*)d_in[1];
    const float* lb    = (const float*)d_in[2];
    const float* ub    = (const float*)d_in[3];
    const float* W1l   = (const float*)d_in[4];
    const float* b1l   = (const float*)d_in[5];
    const float* W1r   = (const float*)d_in[6];
    const float* b1r   = (const float*)d_in[7];
    const float* att1  = (const float*)d_in[8];
    const float* bias1 = (const float*)d_in[9];
    const float* W2l   = (const float*)d_in[10];
    const float* b2l   = (const float*)d_in[11];
    const float* W2r   = (const float*)d_in[12];
    const float* b2r   = (const float*)d_in[13];
    const float* att2  = (const float*)d_in[14];
    const float* bias2 = (const float*)d_in[15];
    const float* W3    = (const float*)d_in[16];
    const float* b3    = (const float*)d_in[17];

    int n  = in_sizes[0] / CIN;
    int E  = in_sizes[1] / 2;
    int ET = E + n;

    char* ws = (char*)d_ws;
    size_t off = 0;
    auto alloc = [&](size_t nbytes) {
        void* p = ws + off;
        off += (nbytes + 255) & ~(size_t)255;
        return p;
    };
    unsigned short* xl1h = (unsigned short*)alloc((size_t)H * n * 32 * 2);
    unsigned short* xr1h = (unsigned short*)alloc((size_t)H * n * 32 * 2);
    unsigned short* h1b  = (unsigned short*)alloc((size_t)n * D1 * 2);
    unsigned short* xl2h = (unsigned short*)alloc((size_t)H * n * 64 * 2);
    unsigned short* xr2h = (unsigned short*)alloc((size_t)H * n * 64 * 2);
    unsigned short* o2h  = (unsigned short*)alloc((size_t)H * n * 64 * 2);
    unsigned short* W2t  = (unsigned short*)alloc((size_t)512 * 128 * 2);
    int* deg  = (int*)alloc((size_t)n * 4);
    int* cur  = (int*)alloc((size_t)n * 4);
    int* rp   = (int*)alloc((size_t)n * 4);
    int* eord = (int*)alloc((size_t)ET * 4);

    // ---- W2 convert + CSR build ----
    k_cvtW2<<<256, 256, 0, stream>>>(W2l, W2r, W2t);
    hipMemsetAsync(deg, 0, (size_t)n * 4, stream);
    k_hist<<<(ET + 255) / 256, 256, 0, stream>>>(ei, E, ET, deg);
    k_scan_one<<<1, 1024, 0, stream>>>(deg, rp, cur, n);
    k_fill<<<(ET + 255) / 256, 256, 0, stream>>>(ei, E, ET, rp, cur, eord);

    // XCD-pinned grid: 8 * nb2 blocks, 4 nodes/block, head=(b&7)>>1
    int nbh = (n + 3) / 4;
    int nb2 = (nbh + 1) / 2;
    int gridAgg = 8 * nb2;

    // ---- layer 1 ----
    k_lin1<<<(n + 15) / 16, 256, 0, stream>>>(x, lb, ub, W1l, b1l, W1r, b1r,
                                              xl1h, xr1h, n);
    k_agg1h<<<gridAgg, 256, 0, stream>>>(xl1h, xr1h, att1, bias1, rp, deg,
                                         eord, h1b, n);

    // ---- layer 2 ----
    dim3 g2((n + 127) / 128, 4);
    k_lin2_mfma<<<g2, 256, 0, stream>>>(h1b, W2t, b2l, b2r, xl2h, xr2h, n);
    k_agg2h<<<gridAgg, 256, 0, stream>>>(xl2h, xr2h, att2, rp, deg, eord,
                                         o2h, n);
    k_fin2<<<(n + 15) / 16, 256, 0, stream>>>(o2h, bias2, W3, b3,
                                              (float*)d_out, n);
}

// Round 8
// 216.941 us; speedup vs baseline: 1.3724x; 1.3724x over previous
//
#include <hip/hip_runtime.h>

#define H 4
#define D1 128
#define D2 256
#define CIN 16
#define SLOPE 0.2f
#define LOG2E 1.4426950408889634f

typedef short short8v __attribute__((ext_vector_type(8)));
typedef float float4v __attribute__((ext_vector_type(4)));

__device__ __forceinline__ float bflo(unsigned u) { return __uint_as_float(u << 16); }
// "dirty" high-half unpack: keep low 16 garbage bits (<= 1 bf16 ulp error)
__device__ __forceinline__ float bfdirty(unsigned u) { return __uint_as_float(u); }
__device__ __forceinline__ unsigned short f2bf(float f) {
    unsigned int u = __float_as_uint(f);
    u += 0x7FFFu + ((u >> 16) & 1u);
    return (unsigned short)(u >> 16);
}

// ============ CSR build ============
__global__ void k_hist(const int* __restrict__ ei, int E, int ET,
                       int* __restrict__ deg) {
    int idx = blockIdx.x * blockDim.x + threadIdx.x;
    if (idx >= ET) return;
    int dst = (idx < E) ? ei[E + idx] : idx - E;
    atomicAdd(&deg[dst], 1);
}

__global__ __launch_bounds__(1024) void k_scan_one(
        const int* __restrict__ deg, int* __restrict__ rp,
        int* __restrict__ cur, int n) {
    __shared__ int wsum[16];
    int t = threadIdx.x;
    int lane = t & 63, w = t >> 6;
    int base = t * 32;
    int loc[32];
    int s = 0;
#pragma unroll
    for (int k = 0; k < 32; ++k) {
        int idx = base + k;
        int v = (idx < n) ? deg[idx] : 0;
        loc[k] = s;
        s += v;
    }
    int inc = s;
#pragma unroll
    for (int off = 1; off < 64; off <<= 1) {
        int u = __shfl_up(inc, off, 64);
        if (lane >= off) inc += u;
    }
    int excl = inc - s;
    if (lane == 63) wsum[w] = inc;
    __syncthreads();
    if (w == 0) {
        int v = (lane < 16) ? wsum[lane] : 0;
        int winc = v;
#pragma unroll
        for (int off = 1; off < 16; off <<= 1) {
            int u = __shfl_up(winc, off, 64);
            if (lane >= off) winc += u;
        }
        if (lane < 16) wsum[lane] = winc - v;
    }
    __syncthreads();
    int offw = wsum[w] + excl;
#pragma unroll
    for (int k = 0; k < 32; ++k) {
        int idx = base + k;
        if (idx < n) { rp[idx] = offw + loc[k]; cur[idx] = 0; }
    }
}

__global__ void k_fill(const int* __restrict__ ei, int E, int ET,
                       const int* __restrict__ rp, int* __restrict__ cur,
                       int* __restrict__ eord) {
    int idx = blockIdx.x * blockDim.x + threadIdx.x;
    if (idx >= ET) return;
    int src, dst;
    if (idx < E) { src = ei[idx]; dst = ei[E + idx]; }
    else         { src = dst = idx - E; }
    int pos = atomicAdd(&cur[dst], 1);
    eord[rp[dst] + pos] = src;
}

// ============ fused prep: lin1 | W2 cvt+transpose | zero deg ============
// blocks [0,B1): lin1 (16 nodes each); [B1,B1+256): cvtW2; rest: zero deg.
__global__ __launch_bounds__(256) void k_prep(
        const float* __restrict__ x, const float* __restrict__ lb,
        const float* __restrict__ ub,
        const float* __restrict__ Wl, const float* __restrict__ bl,
        const float* __restrict__ Wr, const float* __restrict__ br,
        unsigned short* __restrict__ xl, float* __restrict__ xr,
        const float* __restrict__ W2l, const float* __restrict__ W2r,
        unsigned short* __restrict__ W2t,
        int* __restrict__ deg, int n, int B1) {
    __shared__ float Wls[CIN][D1];
    __shared__ float Wrs[CIN][D1];
    __shared__ float ys[16][CIN];
    int b = blockIdx.x;
    int t = threadIdx.x;
    if (b >= B1) {
        int rb = b - B1;
        if (rb < 256) {                       // cvtW2
            int idx = rb * 256 + t;           // 0..65535
            int k = idx >> 9, c = idx & 511;
            float v = (c < 256) ? W2l[k * 256 + c] : W2r[k * 256 + (c - 256)];
            W2t[(size_t)c * 128 + k] = f2bf(v);
        } else {                              // zero deg
            int idx = (rb - 256) * 256 + t;
            if (idx < n) deg[idx] = 0;
        }
        return;
    }
    int i0 = b * 16;
#pragma unroll
    for (int i = 0; i < 8; ++i) {
        int flat = t + 256 * i;
        int k = flat >> 7, c = flat & 127;
        Wls[k][c] = Wl[k * D1 + c];
        Wrs[k][c] = Wr[k * D1 + c];
    }
    {
        int node = t >> 4, k = t & 15;
        int gi = i0 + node;
        float xv = (gi < n) ? x[(size_t)gi * CIN + k] : 0.f;
        ys[node][k] = (xv - lb[k]) / (ub[k] - lb[k]);
    }
    __syncthreads();
    int c = t & 127;
    bool left = t < 128;
    const float (*Ws)[D1] = left ? Wls : Wrs;
    float bias = left ? bl[c] : br[c];
    for (int j = 0; j < 16; ++j) {
        float acc = bias;
#pragma unroll
        for (int k = 0; k < CIN; ++k) acc += ys[j][k] * Ws[k][c];
        int gi = i0 + j;
        if (gi < n) {
            if (left) xl[(size_t)gi * D1 + c] = f2bf(acc);
            else      xr[(size_t)gi * D1 + c] = acc;
        }
    }
}

// ============ layer-2 linear: bf16 MFMA GEMM ============
__global__ __launch_bounds__(256) void k_lin2_mfma(
        const unsigned short* __restrict__ h1b,   // [n][128] bf16
        const unsigned short* __restrict__ W2t,   // [512][128] bf16
        const float* __restrict__ b2l, const float* __restrict__ b2r,
        unsigned short* __restrict__ xl2,         // [n][256] bf16
        unsigned short* __restrict__ xr2,         // [n][256] bf16
        int n) {
    __shared__ unsigned short At[128 * 128];
    __shared__ unsigned short Bt[128 * 128];
    int t = threadIdx.x;
    int row0 = blockIdx.x * 128;
    int col0 = blockIdx.y * 128;

    {
        int r = t >> 1, hh = (t & 1) * 64;
        bool ok = (row0 + r) < n;
        const unsigned short* gA = h1b + (size_t)(row0 + r) * 128 + hh;
        const unsigned short* gB = W2t + (size_t)(col0 + r) * 128 + hh;
#pragma unroll
        for (int i = 0; i < 8; ++i) {
            uint4 vA = ok ? *(const uint4*)(gA + i * 8) : make_uint4(0, 0, 0, 0);
            uint4 vB = *(const uint4*)(gB + i * 8);
            int col = hh + i * 8;
            int idx = (r * 128 + col) ^ ((r & 15) << 3);
            *(uint4*)&At[idx] = vA;
            *(uint4*)&Bt[idx] = vB;
        }
    }
    __syncthreads();

    int w = t >> 6, l = t & 63;
    int wr = w >> 1, wc = w & 1;
    float4v acc[4][4];
#pragma unroll
    for (int m = 0; m < 4; ++m)
#pragma unroll
        for (int nn = 0; nn < 4; ++nn) acc[m][nn] = (float4v)0.f;

#pragma unroll
    for (int ks = 0; ks < 4; ++ks) {
        int kb = ks * 32 + ((l >> 4) << 3);
        short8v a[4], b[4];
#pragma unroll
        for (int m = 0; m < 4; ++m) {
            int r = wr * 64 + m * 16 + (l & 15);
            a[m] = *(const short8v*)&At[(r * 128 + kb) ^ ((r & 15) << 3)];
        }
#pragma unroll
        for (int nn = 0; nn < 4; ++nn) {
            int c = wc * 64 + nn * 16 + (l & 15);
            b[nn] = *(const short8v*)&Bt[(c * 128 + kb) ^ ((c & 15) << 3)];
        }
#pragma unroll
        for (int m = 0; m < 4; ++m)
#pragma unroll
            for (int nn = 0; nn < 4; ++nn)
                acc[m][nn] = __builtin_amdgcn_mfma_f32_16x16x32_bf16(
                    a[m], b[nn], acc[m][nn], 0, 0, 0);
    }

    unsigned short* ob = (col0 < 256) ? xl2 : xr2;
    const float* bp = (col0 < 256) ? b2l : b2r;
    int cb = (col0 < 256) ? col0 : col0 - 256;
#pragma unroll
    for (int nn = 0; nn < 4; ++nn) {
        int colc = cb + wc * 64 + nn * 16 + (l & 15);
        float bv = bp[colc];
#pragma unroll
        for (int m = 0; m < 4; ++m) {
            int rbase = row0 + wr * 64 + m * 16 + ((l >> 4) << 2);
#pragma unroll
            for (int r = 0; r < 4; ++r) {
                int row = rbase + r;
                if (row < n)
                    ob[(size_t)row * 256 + colc] = f2bf(acc[m][nn][r] + bv);
            }
        }
    }
}

// ============ fused GATv2 aggregation, layer 1 ============
// 256 thr = 4 nodes (1 wave each); 2 comps/lane; head = 16-lane group.
__global__ __launch_bounds__(256) void k_agg1(
        const unsigned short* __restrict__ xl, const float* __restrict__ xr,
        const float* __restrict__ att, const float* __restrict__ bias,
        const int* __restrict__ rp, const int* __restrict__ deg,
        const int* __restrict__ eord, unsigned short* __restrict__ h1b, int n) {
    int t = threadIdx.x;
    int node = blockIdx.x * 4 + (t >> 6);
    int l = t & 63;
    int nd = (node < n) ? node : n - 1;
    float2 xrv = *(const float2*)(xr + (size_t)nd * D1 + 2 * l);
    float2 av  = *(const float2*)(att + 2 * l);
    av.x *= LOG2E; av.y *= LOG2E;
    int start = __builtin_amdgcn_readfirstlane(rp[nd]);
    int cnt   = (node < n) ? deg[nd] : 0;
    cnt = __builtin_amdgcn_readfirstlane(cnt);
    const unsigned* xlp = (const unsigned*)xl;
    float d = 0.f, a0 = 0.f, a1 = 0.f;
    int cnt4 = cnt & ~3;
    unsigned r0, r1, r2, r3;
    if (cnt4 > 0) {
        int i0 = eord[start + 0], i1 = eord[start + 1];
        int i2 = eord[start + 2], i3 = eord[start + 3];
        r0 = xlp[(size_t)i0 * 64 + l]; r1 = xlp[(size_t)i1 * 64 + l];
        r2 = xlp[(size_t)i2 * 64 + l]; r3 = xlp[(size_t)i3 * 64 + l];
    }
    for (int j = 0; j < cnt4; j += 4) {
        unsigned p0 = r0, p1 = r1, p2 = r2, p3 = r3;
        int jn = j + 4;
        if (jn < cnt4) {
            int i0 = eord[start + jn + 0], i1 = eord[start + jn + 1];
            int i2 = eord[start + jn + 2], i3 = eord[start + jn + 3];
            r0 = xlp[(size_t)i0 * 64 + l]; r1 = xlp[(size_t)i1 * 64 + l];
            r2 = xlp[(size_t)i2 * 64 + l]; r3 = xlp[(size_t)i3 * 64 + l];
        }
        float x00 = bflo(p0), x01 = bfdirty(p0);
        float x10 = bflo(p1), x11 = bfdirty(p1);
        float x20 = bflo(p2), x21 = bfdirty(p2);
        float x30 = bflo(p3), x31 = bfdirty(p3);
        float v, lg0, lg1, lg2, lg3;
        v = x00 + xrv.x; v = fmaxf(v, SLOPE * v); lg0  = av.x * v;
        v = x01 + xrv.y; v = fmaxf(v, SLOPE * v); lg0 += av.y * v;
        v = x10 + xrv.x; v = fmaxf(v, SLOPE * v); lg1  = av.x * v;
        v = x11 + xrv.y; v = fmaxf(v, SLOPE * v); lg1 += av.y * v;
        v = x20 + xrv.x; v = fmaxf(v, SLOPE * v); lg2  = av.x * v;
        v = x21 + xrv.y; v = fmaxf(v, SLOPE * v); lg2 += av.y * v;
        v = x30 + xrv.x; v = fmaxf(v, SLOPE * v); lg3  = av.x * v;
        v = x31 + xrv.y; v = fmaxf(v, SLOPE * v); lg3 += av.y * v;
        lg0 += __shfl_xor(lg0, 8); lg1 += __shfl_xor(lg1, 8);
        lg2 += __shfl_xor(lg2, 8); lg3 += __shfl_xor(lg3, 8);
        lg0 += __shfl_xor(lg0, 4); lg1 += __shfl_xor(lg1, 4);
        lg2 += __shfl_xor(lg2, 4); lg3 += __shfl_xor(lg3, 4);
        lg0 += __shfl_xor(lg0, 2); lg1 += __shfl_xor(lg1, 2);
        lg2 += __shfl_xor(lg2, 2); lg3 += __shfl_xor(lg3, 2);
        lg0 += __shfl_xor(lg0, 1); lg1 += __shfl_xor(lg1, 1);
        lg2 += __shfl_xor(lg2, 1); lg3 += __shfl_xor(lg3, 1);
        float e0 = exp2f(lg0), e1 = exp2f(lg1);
        float e2 = exp2f(lg2), e3 = exp2f(lg3);
        d += (e0 + e1) + (e2 + e3);
        a0 += e0 * x00 + e1 * x10 + e2 * x20 + e3 * x30;
        a1 += e0 * x01 + e1 * x11 + e2 * x21 + e3 * x31;
    }
    for (int j = cnt4; j < cnt; ++j) {
        int s0 = eord[start + j];
        unsigned p0 = xlp[(size_t)s0 * 64 + l];
        float x00 = bflo(p0), x01 = bfdirty(p0);
        float v, lg0;
        v = x00 + xrv.x; v = fmaxf(v, SLOPE * v); lg0  = av.x * v;
        v = x01 + xrv.y; v = fmaxf(v, SLOPE * v); lg0 += av.y * v;
        lg0 += __shfl_xor(lg0, 8);
        lg0 += __shfl_xor(lg0, 4);
        lg0 += __shfl_xor(lg0, 2);
        lg0 += __shfl_xor(lg0, 1);
        float e0 = exp2f(lg0);
        d += e0;
        a0 += e0 * x00;
        a1 += e0 * x01;
    }
    if (node < n) {
        float inv = 1.f / d;
        float o0 = fmaxf(a0 * inv + bias[2 * l + 0], 0.f);
        float o1 = fmaxf(a1 * inv + bias[2 * l + 1], 0.f);
        ((unsigned*)h1b)[(size_t)node * 64 + l] =
            ((unsigned)f2bf(o1) << 16) | f2bf(o0);
    }
}

// ============ fused GATv2 aggregation + head, layer 2 ============
__global__ __launch_bounds__(256) void k_agg2(
        const unsigned short* __restrict__ xl, const unsigned short* __restrict__ xr,
        const float* __restrict__ att, const float* __restrict__ b2,
        const float* __restrict__ W3, const float* __restrict__ b3,
        const int* __restrict__ rp, const int* __restrict__ deg,
        const int* __restrict__ eord, float* __restrict__ out, int n) {
    int t = threadIdx.x;
    int node = blockIdx.x * 4 + (t >> 6);
    int l = t & 63;
    int nd = (node < n) ? node : n - 1;
    const uint2* xrp = (const uint2*)xr;
    uint2 xru = xrp[(size_t)nd * 64 + l];
    float4 xrv = make_float4(bflo(xru.x), bfdirty(xru.x), bflo(xru.y), bfdirty(xru.y));
    float4 av  = *(const float4*)(att + 4 * l);
    av.x *= LOG2E; av.y *= LOG2E; av.z *= LOG2E; av.w *= LOG2E;
    int start = __builtin_amdgcn_readfirstlane(rp[nd]);
    int cnt   = (node < n) ? deg[nd] : 0;
    cnt = __builtin_amdgcn_readfirstlane(cnt);
    const uint2* xlp = (const uint2*)xl;
    float d = 0.f, a0 = 0.f, a1 = 0.f, a2 = 0.f, a3 = 0.f;
    int cnt4 = cnt & ~3;
    uint2 r0, r1, r2, r3;
    if (cnt4 > 0) {
        int i0 = eord[start + 0], i1 = eord[start + 1];
        int i2 = eord[start + 2], i3 = eord[start + 3];
        r0 = xlp[(size_t)i0 * 64 + l]; r1 = xlp[(size_t)i1 * 64 + l];
        r2 = xlp[(size_t)i2 * 64 + l]; r3 = xlp[(size_t)i3 * 64 + l];
    }
    for (int j = 0; j < cnt4; j += 4) {
        uint2 p0 = r0, p1 = r1, p2 = r2, p3 = r3;
        int jn = j + 4;
        if (jn < cnt4) {
            int i0 = eord[start + jn + 0], i1 = eord[start + jn + 1];
            int i2 = eord[start + jn + 2], i3 = eord[start + jn + 3];
            r0 = xlp[(size_t)i0 * 64 + l]; r1 = xlp[(size_t)i1 * 64 + l];
            r2 = xlp[(size_t)i2 * 64 + l]; r3 = xlp[(size_t)i3 * 64 + l];
        }
        float x00 = bflo(p0.x), x01 = bfdirty(p0.x), x02 = bflo(p0.y), x03 = bfdirty(p0.y);
        float x10 = bflo(p1.x), x11 = bfdirty(p1.x), x12 = bflo(p1.y), x13 = bfdirty(p1.y);
        float x20 = bflo(p2.x), x21 = bfdirty(p2.x), x22 = bflo(p2.y), x23 = bfdirty(p2.y);
        float x30 = bflo(p3.x), x31 = bfdirty(p3.x), x32 = bflo(p3.y), x33 = bfdirty(p3.y);
        float v, lg0, lg1, lg2, lg3;
        v = x00 + xrv.x; v = fmaxf(v, SLOPE * v); lg0  = av.x * v;
        v = x01 + xrv.y; v = fmaxf(v, SLOPE * v); lg0 += av.y * v;
        v = x02 + xrv.z; v = fmaxf(v, SLOPE * v); lg0 += av.z * v;
        v = x03 + xrv.w; v = fmaxf(v, SLOPE * v); lg0 += av.w * v;
        v = x10 + xrv.x; v = fmaxf(v, SLOPE * v); lg1  = av.x * v;
        v = x11 + xrv.y; v = fmaxf(v, SLOPE * v); lg1 += av.y * v;
        v = x12 + xrv.z; v = fmaxf(v, SLOPE * v); lg1 += av.z * v;
        v = x13 + xrv.w; v = fmaxf(v, SLOPE * v); lg1 += av.w * v;
        v = x20 + xrv.x; v = fmaxf(v, SLOPE * v); lg2  = av.x * v;
        v = x21 + xrv.y; v = fmaxf(v, SLOPE * v); lg2 += av.y * v;
        v = x22 + xrv.z; v = fmaxf(v, SLOPE * v); lg2 += av.z * v;
        v = x23 + xrv.w; v = fmaxf(v, SLOPE * v); lg2 += av.w * v;
        v = x30 + xrv.x; v = fmaxf(v, SLOPE * v); lg3  = av.x * v;
        v = x31 + xrv.y; v = fmaxf(v, SLOPE * v); lg3 += av.y * v;
        v = x32 + xrv.z; v = fmaxf(v, SLOPE * v); lg3 += av.z * v;
        v = x33 + xrv.w; v = fmaxf(v, SLOPE * v); lg3 += av.w * v;
        lg0 += __shfl_xor(lg0, 8); lg1 += __shfl_xor(lg1, 8);
        lg2 += __shfl_xor(lg2, 8); lg3 += __shfl_xor(lg3, 8);
        lg0 += __shfl_xor(lg0, 4); lg1 += __shfl_xor(lg1, 4);
        lg2 += __shfl_xor(lg2, 4); lg3 += __shfl_xor(lg3, 4);
        lg0 += __shfl_xor(lg0, 2); lg1 += __shfl_xor(lg1, 2);
        lg2 += __shfl_xor(lg2, 2); lg3 += __shfl_xor(lg3, 2);
        lg0 += __shfl_xor(lg0, 1); lg1 += __shfl_xor(lg1, 1);
        lg2 += __shfl_xor(lg2, 1); lg3 += __shfl_xor(lg3, 1);
        float e0 = exp2f(lg0), e1 = exp2f(lg1);
        float e2 = exp2f(lg2), e3 = exp2f(lg3);
        d += (e0 + e1) + (e2 + e3);
        a0 += e0 * x00 + e1 * x10 + e2 * x20 + e3 * x30;
        a1 += e0 * x01 + e1 * x11 + e2 * x21 + e3 * x31;
        a2 += e0 * x02 + e1 * x12 + e2 * x22 + e3 * x32;
        a3 += e0 * x03 + e1 * x13 + e2 * x23 + e3 * x33;
    }
    for (int j = cnt4; j < cnt; ++j) {
        int s0 = eord[start + j];
        uint2 p0 = xlp[(size_t)s0 * 64 + l];
        float x00 = bflo(p0.x), x01 = bfdirty(p0.x), x02 = bflo(p0.y), x03 = bfdirty(p0.y);
        float v, lg0;
        v = x00 + xrv.x; v = fmaxf(v, SLOPE * v); lg0  = av.x * v;
        v = x01 + xrv.y; v = fmaxf(v, SLOPE * v); lg0 += av.y * v;
        v = x02 + xrv.z; v = fmaxf(v, SLOPE * v); lg0 += av.z * v;
        v = x03 + xrv.w; v = fmaxf(v, SLOPE * v); lg0 += av.w * v;
        lg0 += __shfl_xor(lg0, 8);
        lg0 += __shfl_xor(lg0, 4);
        lg0 += __shfl_xor(lg0, 2);
        lg0 += __shfl_xor(lg0, 1);
        float e0 = exp2f(lg0);
        d += e0;
        a0 += e0 * x00; a1 += e0 * x01; a2 += e0 * x02; a3 += e0 * x03;
    }
    float inv = 1.f / d;
    float v0 = a0 * inv, v1 = a1 * inv, v2 = a2 * inv, v3 = a3 * inv;
    v0 += __shfl_xor(v0, 16); v1 += __shfl_xor(v1, 16);
    v2 += __shfl_xor(v2, 16); v3 += __shfl_xor(v3, 16);
    v0 += __shfl_xor(v0, 32); v1 += __shfl_xor(v1, 32);
    v2 += __shfl_xor(v2, 32); v3 += __shfl_xor(v3, 32);
    int c0 = 4 * (l & 15);
    v0 = fmaxf(0.25f * v0 + b2[c0 + 0], 0.f);
    v1 = fmaxf(0.25f * v1 + b2[c0 + 1], 0.f);
    v2 = fmaxf(0.25f * v2 + b2[c0 + 2], 0.f);
    v3 = fmaxf(0.25f * v3 + b2[c0 + 3], 0.f);
    float p0, p1, p2, p3, p4;
    {
        const float* w0 = W3 + (c0 + 0) * 5;
        const float* w1 = W3 + (c0 + 1) * 5;
        const float* w2 = W3 + (c0 + 2) * 5;
        const float* w3 = W3 + (c0 + 3) * 5;
        p0 = v0 * w0[0] + v1 * w1[0] + v2 * w2[0] + v3 * w3[0];
        p1 = v0 * w0[1] + v1 * w1[1] + v2 * w2[1] + v3 * w3[1];
        p2 = v0 * w0[2] + v1 * w1[2] + v2 * w2[2] + v3 * w3[2];
        p3 = v0 * w0[3] + v1 * w1[3] + v2 * w2[3] + v3 * w3[3];
        p4 = v0 * w0[4] + v1 * w1[4] + v2 * w2[4] + v3 * w3[4];
    }
#pragma unroll
    for (int off = 1; off < 16; off <<= 1) {
        p0 += __shfl_xor(p0, off); p1 += __shfl_xor(p1, off);
        p2 += __shfl_xor(p2, off); p3 += __shfl_xor(p3, off);
        p4 += __shfl_xor(p4, off);
    }
    if (l == 0 && node < n) {
        float* o = out + (size_t)node * 5;
        o[0] = 1.f / (1.f + __expf(-(p0 + b3[0])));
        o[1] = 1.f / (1.f + __expf(-(p1 + b3[1])));
        o[2] = 1.f / (1.f + __expf(-(p2 + b3[2])));
        o[3] = 1.f / (1.f + __expf(-(p3 + b3[3])));
        o[4] = 1.f / (1.f + __expf(-(p4 + b3[4])));
    }
}

extern "C" void kernel_launch(void* const* d_in, const int* in_sizes, int n_in,
                              void* d_out, int out_size, void* d_ws, size_t ws_size,
                              hipStream_t stream) {
    const float* x     = (const float*)d_in[0];
    const int*   ei    = (const int*)d_in[1];
    const float* lb    = (const float*)d_in[2];
    const float* ub    = (const float*)d_in[3];
    const float* W1l   = (const float*)d_in[4];
    const float* b1l   = (const float*)d_in[5];
    const float* W1r   = (const float*)d_in[6];
    const float* b1r   = (const float*)d_in[7];
    const float* att1  = (const float*)d_in[8];
    const float* bias1 = (const float*)d_in[9];
    const float* W2l   = (const float*)d_in[10];
    const float* b2l   = (const float*)d_in[11];
    const float* W2r   = (const float*)d_in[12];
    const float* b2r   = (const float*)d_in[13];
    const float* att2  = (const float*)d_in[14];
    const float* bias2 = (const float*)d_in[15];
    const float* W3    = (const float*)d_in[16];
    const float* b3    = (const float*)d_in[17];

    int n  = in_sizes[0] / CIN;
    int E  = in_sizes[1] / 2;
    int ET = E + n;

    char* ws = (char*)d_ws;
    size_t off = 0;
    auto alloc = [&](size_t nbytes) {
        void* p = ws + off;
        off += (nbytes + 255) & ~(size_t)255;
        return p;
    };
    unsigned short* xl1 = (unsigned short*)alloc((size_t)n * D1 * 2);
    float*          xr1 = (float*)alloc((size_t)n * D1 * 4);
    unsigned short* h1b = (unsigned short*)alloc((size_t)n * D1 * 2);
    unsigned short* xl2 = (unsigned short*)alloc((size_t)n * D2 * 2);
    unsigned short* xr2 = (unsigned short*)alloc((size_t)n * D2 * 2);
    unsigned short* W2t = (unsigned short*)alloc((size_t)512 * 128 * 2);
    int* deg  = (int*)alloc((size_t)n * 4);
    int* cur  = (int*)alloc((size_t)n * 4);
    int* rp   = (int*)alloc((size_t)n * 4);
    int* eord = (int*)alloc((size_t)ET * 4);

    // ---- prep: lin1 + cvtW2 + zero deg (one launch) ----
    int B1 = (n + 15) / 16;
    int BZ = (n + 255) / 256;
    k_prep<<<B1 + 256 + BZ, 256, 0, stream>>>(
        x, lb, ub, W1l, b1l, W1r, b1r, xl1, xr1, W2l, W2r, W2t, deg, n, B1);

    // ---- CSR build ----
    k_hist<<<(ET + 255) / 256, 256, 0, stream>>>(ei, E, ET, deg);
    k_scan_one<<<1, 1024, 0, stream>>>(deg, rp, cur, n);
    k_fill<<<(ET + 255) / 256, 256, 0, stream>>>(ei, E, ET, rp, cur, eord);

    // ---- layer 1 aggregation ----
    k_agg1<<<(n + 3) / 4, 256, 0, stream>>>(xl1, xr1, att1, bias1, rp, deg,
                                            eord, h1b, n);

    // ---- layer 2 ----
    dim3 g2((n + 127) / 128, 4);
    k_lin2_mfma<<<g2, 256, 0, stream>>>(h1b, W2t, b2l, b2r, xl2, xr2, n);
    k_agg2<<<(n + 3) / 4, 256, 0, stream>>>(xl2, xr2, att2, bias2, W3, b3,
                                            rp, deg, eord, (float*)d_out, n);
}

// Round 9
// 181.671 us; speedup vs baseline: 1.6389x; 1.1941x over previous
//
#include <hip/hip_runtime.h>

#define H 4
#define D1 128
#define D2 256
#define CIN 16
#define SLOPE 0.2f
#define LOG2E 1.4426950408889634f

typedef short short8v __attribute__((ext_vector_type(8)));
typedef float float4v __attribute__((ext_vector_type(4)));
typedef float float2v __attribute__((ext_vector_type(2)));

__device__ __forceinline__ float bflo(unsigned u) { return __uint_as_float(u << 16); }
// "dirty" high-half unpack: keep low 16 garbage bits (<= 1 bf16 ulp error)
__device__ __forceinline__ float bfdirty(unsigned u) { return __uint_as_float(u); }
__device__ __forceinline__ unsigned short f2bf(float f) {
    unsigned int u = __float_as_uint(f);
    u += 0x7FFFu + ((u >> 16) & 1u);
    return (unsigned short)(u >> 16);
}
// pack two floats -> two OCP e4m3 fp8 bytes (low 16 bits)
__device__ __forceinline__ unsigned short f2fp8x2(float a, float b) {
    return (unsigned short)__builtin_amdgcn_cvt_pk_fp8_f32(a, b, 0, false);
}

// ============ CSR build ============
__global__ void k_hist(const int* __restrict__ ei, int E, int ET,
                       int* __restrict__ deg) {
    int idx = blockIdx.x * blockDim.x + threadIdx.x;
    if (idx >= ET) return;
    int dst = (idx < E) ? ei[E + idx] : idx - E;
    atomicAdd(&deg[dst], 1);
}

__global__ __launch_bounds__(1024) void k_scan_one(
        const int* __restrict__ deg, int* __restrict__ rp,
        int* __restrict__ cur, int n) {
    __shared__ int wsum[16];
    int t = threadIdx.x;
    int lane = t & 63, w = t >> 6;
    int base = t * 32;
    int vals[32];
    const int4* dp = (const int4*)deg;
#pragma unroll
    for (int q = 0; q < 8; ++q) {
        int4 v = dp[(base >> 2) + q];   // in-bounds of d_ws (later buffers follow)
        vals[4 * q + 0] = v.x; vals[4 * q + 1] = v.y;
        vals[4 * q + 2] = v.z; vals[4 * q + 3] = v.w;
    }
    int loc[32];
    int s = 0;
#pragma unroll
    for (int k = 0; k < 32; ++k) {
        int idx = base + k;
        int v = (idx < n) ? vals[k] : 0;
        loc[k] = s;
        s += v;
    }
    int inc = s;
#pragma unroll
    for (int off = 1; off < 64; off <<= 1) {
        int u = __shfl_up(inc, off, 64);
        if (lane >= off) inc += u;
    }
    int excl = inc - s;
    if (lane == 63) wsum[w] = inc;
    __syncthreads();
    if (w == 0) {
        int v = (lane < 16) ? wsum[lane] : 0;
        int winc = v;
#pragma unroll
        for (int off = 1; off < 16; off <<= 1) {
            int u = __shfl_up(winc, off, 64);
            if (lane >= off) winc += u;
        }
        if (lane < 16) wsum[lane] = winc - v;
    }
    __syncthreads();
    int offw = wsum[w] + excl;
#pragma unroll
    for (int q = 0; q < 8; ++q) {
        int i0 = base + 4 * q;
        if (i0 + 3 < n) {
            *(int4*)(rp + i0) = make_int4(offw + loc[4 * q + 0], offw + loc[4 * q + 1],
                                          offw + loc[4 * q + 2], offw + loc[4 * q + 3]);
            *(int4*)(cur + i0) = make_int4(0, 0, 0, 0);
        } else {
#pragma unroll
            for (int e = 0; e < 4; ++e) {
                int idx = i0 + e;
                if (idx < n) { rp[idx] = offw + loc[4 * q + e]; cur[idx] = 0; }
            }
        }
    }
}

__global__ void k_fill(const int* __restrict__ ei, int E, int ET,
                       const int* __restrict__ rp, int* __restrict__ cur,
                       int* __restrict__ eord) {
    int idx = blockIdx.x * blockDim.x + threadIdx.x;
    if (idx >= ET) return;
    int src, dst;
    if (idx < E) { src = ei[idx]; dst = ei[E + idx]; }
    else         { src = dst = idx - E; }
    int pos = atomicAdd(&cur[dst], 1);
    eord[rp[dst] + pos] = src;
}

// ============ fused prep: lin1 | W2 cvt+transpose | zero deg ============
__global__ __launch_bounds__(256) void k_prep(
        const float* __restrict__ x, const float* __restrict__ lb,
        const float* __restrict__ ub,
        const float* __restrict__ Wl, const float* __restrict__ bl,
        const float* __restrict__ Wr, const float* __restrict__ br,
        unsigned char* __restrict__ xl8, float* __restrict__ xr,
        const float* __restrict__ W2l, const float* __restrict__ W2r,
        unsigned short* __restrict__ W2t,
        int* __restrict__ deg, int n, int B1) {
    __shared__ float Wls[CIN][D1];
    __shared__ float Wrs[CIN][D1];
    __shared__ float ys[16][CIN];
    int b = blockIdx.x;
    int t = threadIdx.x;
    if (b >= B1) {
        int rb = b - B1;
        if (rb < 256) {                       // cvtW2
            int idx = rb * 256 + t;           // 0..65535
            int k = idx >> 9, c = idx & 511;
            float v = (c < 256) ? W2l[k * 256 + c] : W2r[k * 256 + (c - 256)];
            W2t[(size_t)c * 128 + k] = f2bf(v);
        } else {                              // zero deg
            int idx = (rb - 256) * 256 + t;
            if (idx < n) deg[idx] = 0;
        }
        return;
    }
    int i0 = b * 16;
#pragma unroll
    for (int i = 0; i < 8; ++i) {
        int flat = t + 256 * i;
        int k = flat >> 7, c = flat & 127;
        Wls[k][c] = Wl[k * D1 + c];
        Wrs[k][c] = Wr[k * D1 + c];
    }
    {
        int node = t >> 4, k = t & 15;
        int gi = i0 + node;
        float xv = (gi < n) ? x[(size_t)gi * CIN + k] : 0.f;
        ys[node][k] = (xv - lb[k]) / (ub[k] - lb[k]);
    }
    __syncthreads();
    int c = t & 127;
    bool left = t < 128;   // waves 0,1 left; 2,3 right (wave-uniform)
    const float (*Ws)[D1] = left ? Wls : Wrs;
    float bias = left ? bl[c] : br[c];
    for (int j = 0; j < 16; ++j) {
        float acc = bias;
#pragma unroll
        for (int k = 0; k < CIN; ++k) acc += ys[j][k] * Ws[k][c];
        int gi = i0 + j;
        float other = __shfl_xor(acc, 1);
        if (gi < n) {
            if (left) {
                if (!(c & 1))
                    *(unsigned short*)(xl8 + (size_t)gi * D1 + c) = f2fp8x2(acc, other);
            } else {
                xr[(size_t)gi * D1 + c] = acc;
            }
        }
    }
}

// ============ layer-2 linear: bf16 MFMA GEMM; xl2 out fp8, xr2 out bf16 ====
__global__ __launch_bounds__(256) void k_lin2_mfma(
        const unsigned short* __restrict__ h1b,   // [n][128] bf16
        const unsigned short* __restrict__ W2t,   // [512][128] bf16
        const float* __restrict__ b2l, const float* __restrict__ b2r,
        unsigned char* __restrict__ xl2,          // [n][256] fp8
        unsigned short* __restrict__ xr2,         // [n][256] bf16
        int n) {
    __shared__ unsigned short At[128 * 128];
    __shared__ unsigned short Bt[128 * 128];
    int t = threadIdx.x;
    int row0 = blockIdx.x * 128;
    int col0 = blockIdx.y * 128;

    {
        int r = t >> 1, hh = (t & 1) * 64;
        bool ok = (row0 + r) < n;
        const unsigned short* gA = h1b + (size_t)(row0 + r) * 128 + hh;
        const unsigned short* gB = W2t + (size_t)(col0 + r) * 128 + hh;
#pragma unroll
        for (int i = 0; i < 8; ++i) {
            uint4 vA = ok ? *(const uint4*)(gA + i * 8) : make_uint4(0, 0, 0, 0);
            uint4 vB = *(const uint4*)(gB + i * 8);
            int col = hh + i * 8;
            int idx = (r * 128 + col) ^ ((r & 15) << 3);
            *(uint4*)&At[idx] = vA;
            *(uint4*)&Bt[idx] = vB;
        }
    }
    __syncthreads();

    int w = t >> 6, l = t & 63;
    int wr = w >> 1, wc = w & 1;
    float4v acc[4][4];
#pragma unroll
    for (int m = 0; m < 4; ++m)
#pragma unroll
        for (int nn = 0; nn < 4; ++nn) acc[m][nn] = (float4v)0.f;

#pragma unroll
    for (int ks = 0; ks < 4; ++ks) {
        int kb = ks * 32 + ((l >> 4) << 3);
        short8v a[4], b[4];
#pragma unroll
        for (int m = 0; m < 4; ++m) {
            int r = wr * 64 + m * 16 + (l & 15);
            a[m] = *(const short8v*)&At[(r * 128 + kb) ^ ((r & 15) << 3)];
        }
#pragma unroll
        for (int nn = 0; nn < 4; ++nn) {
            int c = wc * 64 + nn * 16 + (l & 15);
            b[nn] = *(const short8v*)&Bt[(c * 128 + kb) ^ ((c & 15) << 3)];
        }
#pragma unroll
        for (int m = 0; m < 4; ++m)
#pragma unroll
            for (int nn = 0; nn < 4; ++nn)
                acc[m][nn] = __builtin_amdgcn_mfma_f32_16x16x32_bf16(
                    a[m], b[nn], acc[m][nn], 0, 0, 0);
    }

    if (col0 < 256) {
        // fp8 output, pair lanes (colc even|odd) and store ushort
        const float* bp = b2l;
        int cb = col0;
#pragma unroll
        for (int nn = 0; nn < 4; ++nn) {
            int colc = cb + wc * 64 + nn * 16 + (l & 15);
            float bv = bp[colc];
#pragma unroll
            for (int m = 0; m < 4; ++m) {
                int rbase = row0 + wr * 64 + m * 16 + ((l >> 4) << 2);
#pragma unroll
                for (int r = 0; r < 4; ++r) {
                    int row = rbase + r;
                    float val = acc[m][nn][r] + bv;
                    float other = __shfl_xor(val, 1);
                    if (!(l & 1) && row < n)
                        *(unsigned short*)(xl2 + (size_t)row * 256 + colc) =
                            f2fp8x2(val, other);
                }
            }
        }
    } else {
        const float* bp = b2r;
        int cb = col0 - 256;
#pragma unroll
        for (int nn = 0; nn < 4; ++nn) {
            int colc = cb + wc * 64 + nn * 16 + (l & 15);
            float bv = bp[colc];
#pragma unroll
            for (int m = 0; m < 4; ++m) {
                int rbase = row0 + wr * 64 + m * 16 + ((l >> 4) << 2);
#pragma unroll
                for (int r = 0; r < 4; ++r) {
                    int row = rbase + r;
                    if (row < n)
                        xr2[(size_t)row * 256 + colc] = f2bf(acc[m][nn][r] + bv);
                }
            }
        }
    }
}

// ============ fused GATv2 aggregation, layer 1 (fp8 gather table) ============
// 256 thr = 4 nodes (1 wave each); 2 comps/lane; head = 16-lane group.
__global__ __launch_bounds__(256) void k_agg1(
        const unsigned char* __restrict__ xl8, const float* __restrict__ xr,
        const float* __restrict__ att, const float* __restrict__ bias,
        const int* __restrict__ rp, const int* __restrict__ deg,
        const int* __restrict__ eord, unsigned short* __restrict__ h1b, int n) {
    int t = threadIdx.x;
    int node = blockIdx.x * 4 + (t >> 6);
    int l = t & 63;
    int nd = (node < n) ? node : n - 1;
    float2 xrv = *(const float2*)(xr + (size_t)nd * D1 + 2 * l);
    float2 av  = *(const float2*)(att + 2 * l);
    av.x *= LOG2E; av.y *= LOG2E;
    int start = __builtin_amdgcn_readfirstlane(rp[nd]);
    int cnt   = (node < n) ? deg[nd] : 0;
    cnt = __builtin_amdgcn_readfirstlane(cnt);
    const unsigned short* xlp = (const unsigned short*)xl8;  // row = 64 ushorts
    float d = 0.f, a0 = 0.f, a1 = 0.f;
    int cnt4 = cnt & ~3;
    unsigned r0, r1, r2, r3;
    if (cnt4 > 0) {
        int i0 = eord[start + 0], i1 = eord[start + 1];
        int i2 = eord[start + 2], i3 = eord[start + 3];
        r0 = xlp[(size_t)i0 * 64 + l]; r1 = xlp[(size_t)i1 * 64 + l];
        r2 = xlp[(size_t)i2 * 64 + l]; r3 = xlp[(size_t)i3 * 64 + l];
    }
    for (int j = 0; j < cnt4; j += 4) {
        unsigned p0 = r0, p1 = r1, p2 = r2, p3 = r3;
        int jn = j + 4;
        if (jn < cnt4) {
            int i0 = eord[start + jn + 0], i1 = eord[start + jn + 1];
            int i2 = eord[start + jn + 2], i3 = eord[start + jn + 3];
            r0 = xlp[(size_t)i0 * 64 + l]; r1 = xlp[(size_t)i1 * 64 + l];
            r2 = xlp[(size_t)i2 * 64 + l]; r3 = xlp[(size_t)i3 * 64 + l];
        }
        float2v f0 = __builtin_amdgcn_cvt_pk_f32_fp8(p0, false);
        float2v f1 = __builtin_amdgcn_cvt_pk_f32_fp8(p1, false);
        float2v f2 = __builtin_amdgcn_cvt_pk_f32_fp8(p2, false);
        float2v f3 = __builtin_amdgcn_cvt_pk_f32_fp8(p3, false);
        float x00 = f0.x, x01 = f0.y;
        float x10 = f1.x, x11 = f1.y;
        float x20 = f2.x, x21 = f2.y;
        float x30 = f3.x, x31 = f3.y;
        float v, lg0, lg1, lg2, lg3;
        v = x00 + xrv.x; v = fmaxf(v, SLOPE * v); lg0  = av.x * v;
        v = x01 + xrv.y; v = fmaxf(v, SLOPE * v); lg0 += av.y * v;
        v = x10 + xrv.x; v = fmaxf(v, SLOPE * v); lg1  = av.x * v;
        v = x11 + xrv.y; v = fmaxf(v, SLOPE * v); lg1 += av.y * v;
        v = x20 + xrv.x; v = fmaxf(v, SLOPE * v); lg2  = av.x * v;
        v = x21 + xrv.y; v = fmaxf(v, SLOPE * v); lg2 += av.y * v;
        v = x30 + xrv.x; v = fmaxf(v, SLOPE * v); lg3  = av.x * v;
        v = x31 + xrv.y; v = fmaxf(v, SLOPE * v); lg3 += av.y * v;
        lg0 += __shfl_xor(lg0, 8); lg1 += __shfl_xor(lg1, 8);
        lg2 += __shfl_xor(lg2, 8); lg3 += __shfl_xor(lg3, 8);
        lg0 += __shfl_xor(lg0, 4); lg1 += __shfl_xor(lg1, 4);
        lg2 += __shfl_xor(lg2, 4); lg3 += __shfl_xor(lg3, 4);
        lg0 += __shfl_xor(lg0, 2); lg1 += __shfl_xor(lg1, 2);
        lg2 += __shfl_xor(lg2, 2); lg3 += __shfl_xor(lg3, 2);
        lg0 += __shfl_xor(lg0, 1); lg1 += __shfl_xor(lg1, 1);
        lg2 += __shfl_xor(lg2, 1); lg3 += __shfl_xor(lg3, 1);
        float e0 = exp2f(lg0), e1 = exp2f(lg1);
        float e2 = exp2f(lg2), e3 = exp2f(lg3);
        d += (e0 + e1) + (e2 + e3);
        a0 += e0 * x00 + e1 * x10 + e2 * x20 + e3 * x30;
        a1 += e0 * x01 + e1 * x11 + e2 * x21 + e3 * x31;
    }
    for (int j = cnt4; j < cnt; ++j) {
        int s0 = eord[start + j];
        unsigned p0 = xlp[(size_t)s0 * 64 + l];
        float2v f0 = __builtin_amdgcn_cvt_pk_f32_fp8(p0, false);
        float x00 = f0.x, x01 = f0.y;
        float v, lg0;
        v = x00 + xrv.x; v = fmaxf(v, SLOPE * v); lg0  = av.x * v;
        v = x01 + xrv.y; v = fmaxf(v, SLOPE * v); lg0 += av.y * v;
        lg0 += __shfl_xor(lg0, 8);
        lg0 += __shfl_xor(lg0, 4);
        lg0 += __shfl_xor(lg0, 2);
        lg0 += __shfl_xor(lg0, 1);
        float e0 = exp2f(lg0);
        d += e0;
        a0 += e0 * x00;
        a1 += e0 * x01;
    }
    if (node < n) {
        float inv = 1.f / d;
        float o0 = fmaxf(a0 * inv + bias[2 * l + 0], 0.f);
        float o1 = fmaxf(a1 * inv + bias[2 * l + 1], 0.f);
        ((unsigned*)h1b)[(size_t)node * 64 + l] =
            ((unsigned)f2bf(o1) << 16) | f2bf(o0);
    }
}

// ============ fused GATv2 aggregation + head, layer 2 (fp8 gather) ============
__global__ __launch_bounds__(256) void k_agg2(
        const unsigned char* __restrict__ xl8, const unsigned short* __restrict__ xr,
        const float* __restrict__ att, const float* __restrict__ b2,
        const float* __restrict__ W3, const float* __restrict__ b3,
        const int* __restrict__ rp, const int* __restrict__ deg,
        const int* __restrict__ eord, float* __restrict__ out, int n) {
    int t = threadIdx.x;
    int node = blockIdx.x * 4 + (t >> 6);
    int l = t & 63;
    int nd = (node < n) ? node : n - 1;
    const uint2* xrp = (const uint2*)xr;
    uint2 xru = xrp[(size_t)nd * 64 + l];
    float4 xrv = make_float4(bflo(xru.x), bfdirty(xru.x), bflo(xru.y), bfdirty(xru.y));
    float4 av  = *(const float4*)(att + 4 * l);
    av.x *= LOG2E; av.y *= LOG2E; av.z *= LOG2E; av.w *= LOG2E;
    int start = __builtin_amdgcn_readfirstlane(rp[nd]);
    int cnt   = (node < n) ? deg[nd] : 0;
    cnt = __builtin_amdgcn_readfirstlane(cnt);
    const unsigned* xlp = (const unsigned*)xl8;   // row = 64 uints (256 fp8)
    float d = 0.f, a0 = 0.f, a1 = 0.f, a2 = 0.f, a3 = 0.f;
    int cnt4 = cnt & ~3;
    unsigned r0, r1, r2, r3;
    if (cnt4 > 0) {
        int i0 = eord[start + 0], i1 = eord[start + 1];
        int i2 = eord[start + 2], i3 = eord[start + 3];
        r0 = xlp[(size_t)i0 * 64 + l]; r1 = xlp[(size_t)i1 * 64 + l];
        r2 = xlp[(size_t)i2 * 64 + l]; r3 = xlp[(size_t)i3 * 64 + l];
    }
    for (int j = 0; j < cnt4; j += 4) {
        unsigned p0 = r0, p1 = r1, p2 = r2, p3 = r3;
        int jn = j + 4;
        if (jn < cnt4) {
            int i0 = eord[start + jn + 0], i1 = eord[start + jn + 1];
            int i2 = eord[start + jn + 2], i3 = eord[start + jn + 3];
            r0 = xlp[(size_t)i0 * 64 + l]; r1 = xlp[(size_t)i1 * 64 + l];
            r2 = xlp[(size_t)i2 * 64 + l]; r3 = xlp[(size_t)i3 * 64 + l];
        }
        float2v lo0 = __builtin_amdgcn_cvt_pk_f32_fp8(p0, false);
        float2v hi0 = __builtin_amdgcn_cvt_pk_f32_fp8(p0, true);
        float2v lo1 = __builtin_amdgcn_cvt_pk_f32_fp8(p1, false);
        float2v hi1 = __builtin_amdgcn_cvt_pk_f32_fp8(p1, true);
        float2v lo2 = __builtin_amdgcn_cvt_pk_f32_fp8(p2, false);
        float2v hi2 = __builtin_amdgcn_cvt_pk_f32_fp8(p2, true);
        float2v lo3 = __builtin_amdgcn_cvt_pk_f32_fp8(p3, false);
        float2v hi3 = __builtin_amdgcn_cvt_pk_f32_fp8(p3, true);
        float x00 = lo0.x, x01 = lo0.y, x02 = hi0.x, x03 = hi0.y;
        float x10 = lo1.x, x11 = lo1.y, x12 = hi1.x, x13 = hi1.y;
        float x20 = lo2.x, x21 = lo2.y, x22 = hi2.x, x23 = hi2.y;
        float x30 = lo3.x, x31 = lo3.y, x32 = hi3.x, x33 = hi3.y;
        float v, lg0, lg1, lg2, lg3;
        v = x00 + xrv.x; v = fmaxf(v, SLOPE * v); lg0  = av.x * v;
        v = x01 + xrv.y; v = fmaxf(v, SLOPE * v); lg0 += av.y * v;
        v = x02 + xrv.z; v = fmaxf(v, SLOPE * v); lg0 += av.z * v;
        v = x03 + xrv.w; v = fmaxf(v, SLOPE * v); lg0 += av.w * v;
        v = x10 + xrv.x; v = fmaxf(v, SLOPE * v); lg1  = av.x * v;
        v = x11 + xrv.y; v = fmaxf(v, SLOPE * v); lg1 += av.y * v;
        v = x12 + xrv.z; v = fmaxf(v, SLOPE * v); lg1 += av.z * v;
        v = x13 + xrv.w; v = fmaxf(v, SLOPE * v); lg1 += av.w * v;
        v = x20 + xrv.x; v = fmaxf(v, SLOPE * v); lg2  = av.x * v;
        v = x21 + xrv.y; v = fmaxf(v, SLOPE * v); lg2 += av.y * v;
        v = x22 + xrv.z; v = fmaxf(v, SLOPE * v); lg2 += av.z * v;
        v = x23 + xrv.w; v = fmaxf(v, SLOPE * v); lg2 += av.w * v;
        v = x30 + xrv.x; v = fmaxf(v, SLOPE * v); lg3  = av.x * v;
        v = x31 + xrv.y; v = fmaxf(v, SLOPE * v); lg3 += av.y * v;
        v = x32 + xrv.z; v = fmaxf(v, SLOPE * v); lg3 += av.z * v;
        v = x33 + xrv.w; v = fmaxf(v, SLOPE * v); lg3 += av.w * v;
        lg0 += __shfl_xor(lg0, 8); lg1 += __shfl_xor(lg1, 8);
        lg2 += __shfl_xor(lg2, 8); lg3 += __shfl_xor(lg3, 8);
        lg0 += __shfl_xor(lg0, 4); lg1 += __shfl_xor(lg1, 4);
        lg2 += __shfl_xor(lg2, 4); lg3 += __shfl_xor(lg3, 4);
        lg0 += __shfl_xor(lg0, 2); lg1 += __shfl_xor(lg1, 2);
        lg2 += __shfl_xor(lg2, 2); lg3 += __shfl_xor(lg3, 2);
        lg0 += __shfl_xor(lg0, 1); lg1 += __shfl_xor(lg1, 1);
        lg2 += __shfl_xor(lg2, 1); lg3 += __shfl_xor(lg3, 1);
        float e0 = exp2f(lg0), e1 = exp2f(lg1);
        float e2 = exp2f(lg2), e3 = exp2f(lg3);
        d += (e0 + e1) + (e2 + e3);
        a0 += e0 * x00 + e1 * x10 + e2 * x20 + e3 * x30;
        a1 += e0 * x01 + e1 * x11 + e2 * x21 + e3 * x31;
        a2 += e0 * x02 + e1 * x12 + e2 * x22 + e3 * x32;
        a3 += e0 * x03 + e1 * x13 + e2 * x23 + e3 * x33;
    }
    for (int j = cnt4; j < cnt; ++j) {
        int s0 = eord[start + j];
        unsigned p0 = xlp[(size_t)s0 * 64 + l];
        float2v lo0 = __builtin_amdgcn_cvt_pk_f32_fp8(p0, false);
        float2v hi0 = __builtin_amdgcn_cvt_pk_f32_fp8(p0, true);
        float x00 = lo0.x, x01 = lo0.y, x02 = hi0.x, x03 = hi0.y;
        float v, lg0;
        v = x00 + xrv.x; v = fmaxf(v, SLOPE * v); lg0  = av.x * v;
        v = x01 + xrv.y; v = fmaxf(v, SLOPE * v); lg0 += av.y * v;
        v = x02 + xrv.z; v = fmaxf(v, SLOPE * v); lg0 += av.z * v;
        v = x03 + xrv.w; v = fmaxf(v, SLOPE * v); lg0 += av.w * v;
        lg0 += __shfl_xor(lg0, 8);
        lg0 += __shfl_xor(lg0, 4);
        lg0 += __shfl_xor(lg0, 2);
        lg0 += __shfl_xor(lg0, 1);
        float e0 = exp2f(lg0);
        d += e0;
        a0 += e0 * x00; a1 += e0 * x01; a2 += e0 * x02; a3 += e0 * x03;
    }
    float inv = 1.f / d;
    float v0 = a0 * inv, v1 = a1 * inv, v2 = a2 * inv, v3 = a3 * inv;
    v0 += __shfl_xor(v0, 16); v1 += __shfl_xor(v1, 16);
    v2 += __shfl_xor(v2, 16); v3 += __shfl_xor(v3, 16);
    v0 += __shfl_xor(v0, 32); v1 += __shfl_xor(v1, 32);
    v2 += __shfl_xor(v2, 32); v3 += __shfl_xor(v3, 32);
    int c0 = 4 * (l & 15);
    v0 = fmaxf(0.25f * v0 + b2[c0 + 0], 0.f);
    v1 = fmaxf(0.25f * v1 + b2[c0 + 1], 0.f);
    v2 = fmaxf(0.25f * v2 + b2[c0 + 2], 0.f);
    v3 = fmaxf(0.25f * v3 + b2[c0 + 3], 0.f);
    float p0, p1, p2, p3, p4;
    {
        const float* w0 = W3 + (c0 + 0) * 5;
        const float* w1 = W3 + (c0 + 1) * 5;
        const float* w2 = W3 + (c0 + 2) * 5;
        const float* w3 = W3 + (c0 + 3) * 5;
        p0 = v0 * w0[0] + v1 * w1[0] + v2 * w2[0] + v3 * w3[0];
        p1 = v0 * w0[1] + v1 * w1[1] + v2 * w2[1] + v3 * w3[1];
        p2 = v0 * w0[2] + v1 * w1[2] + v2 * w2[2] + v3 * w3[2];
        p3 = v0 * w0[3] + v1 * w1[3] + v2 * w2[3] + v3 * w3[3];
        p4 = v0 * w0[4] + v1 * w1[4] + v2 * w2[4] + v3 * w3[4];
    }
#pragma unroll
    for (int off = 1; off < 16; off <<= 1) {
        p0 += __shfl_xor(p0, off); p1 += __shfl_xor(p1, off);
        p2 += __shfl_xor(p2, off); p3 += __shfl_xor(p3, off);
        p4 += __shfl_xor(p4, off);
    }
    if (l == 0 && node < n) {
        float* o = out + (size_t)node * 5;
        o[0] = 1.f / (1.f + __expf(-(p0 + b3[0])));
        o[1] = 1.f / (1.f + __expf(-(p1 + b3[1])));
        o[2] = 1.f / (1.f + __expf(-(p2 + b3[2])));
        o[3] = 1.f / (1.f + __expf(-(p3 + b3[3])));
        o[4] = 1.f / (1.f + __expf(-(p4 + b3[4])));
    }
}

extern "C" void kernel_launch(void* const* d_in, const int* in_sizes, int n_in,
                              void* d_out, int out_size, void* d_ws, size_t ws_size,
                              hipStream_t stream) {
    const float* x     = (const float*)d_in[0];
    const int*   ei    = (const int*)d_in[1];
    const float* lb    = (const float*)d_in[2];
    const float* ub    = (const float*)d_in[3];
    const float* W1l   = (const float*)d_in[4];
    const float* b1l   = (const float*)d_in[5];
    const float* W1r   = (const float*)d_in[6];
    const float* b1r   = (const float*)d_in[7];
    const float* att1  = (const float*)d_in[8];
    const float* bias1 = (const float*)d_in[9];
    const float* W2l   = (const float*)d_in[10];
    const float* b2l   = (const float*)d_in[11];
    const float* W2r   = (const float*)d_in[12];
    const float* b2r   = (const float*)d_in[13];
    const float* att2  = (const float*)d_in[14];
    const float* bias2 = (const float*)d_in[15];
    const float* W3    = (const float*)d_in[16];
    const float* b3    = (const float*)d_in[17];

    int n  = in_sizes[0] / CIN;
    int E  = in_sizes[1] / 2;
    int ET = E + n;

    char* ws = (char*)d_ws;
    size_t off = 0;
    auto alloc = [&](size_t nbytes) {
        void* p = ws + off;
        off += (nbytes + 255) & ~(size_t)255;
        return p;
    };
    unsigned char*  xl1 = (unsigned char*)alloc((size_t)n * D1);        // fp8
    float*          xr1 = (float*)alloc((size_t)n * D1 * 4);
    unsigned short* h1b = (unsigned short*)alloc((size_t)n * D1 * 2);   // bf16
    unsigned char*  xl2 = (unsigned char*)alloc((size_t)n * D2);        // fp8
    unsigned short* xr2 = (unsigned short*)alloc((size_t)n * D2 * 2);   // bf16
    unsigned short* W2t = (unsigned short*)alloc((size_t)512 * 128 * 2);
    int* deg  = (int*)alloc((size_t)n * 4 + 8192);  // pad: scan over-reads int4
    int* cur  = (int*)alloc((size_t)n * 4);
    int* rp   = (int*)alloc((size_t)n * 4);
    int* eord = (int*)alloc((size_t)ET * 4);

    // ---- prep: lin1 + cvtW2 + zero deg (one launch) ----
    int B1 = (n + 15) / 16;
    int BZ = (n + 255) / 256;
    k_prep<<<B1 + 256 + BZ, 256, 0, stream>>>(
        x, lb, ub, W1l, b1l, W1r, b1r, xl1, xr1, W2l, W2r, W2t, deg, n, B1);

    // ---- CSR build ----
    k_hist<<<(ET + 255) / 256, 256, 0, stream>>>(ei, E, ET, deg);
    k_scan_one<<<1, 1024, 0, stream>>>(deg, rp, cur, n);
    k_fill<<<(ET + 255) / 256, 256, 0, stream>>>(ei, E, ET, rp, cur, eord);

    // ---- layer 1 aggregation ----
    k_agg1<<<(n + 3) / 4, 256, 0, stream>>>(xl1, xr1, att1, bias1, rp, deg,
                                            eord, h1b, n);

    // ---- layer 2 ----
    dim3 g2((n + 127) / 128, 4);
    k_lin2_mfma<<<g2, 256, 0, stream>>>(h1b, W2t, b2l, b2r, xl2, xr2, n);
    k_agg2<<<(n + 3) / 4, 256, 0, stream>>>(xl2, xr2, att2, bias2, W3, b3,
                                            rp, deg, eord, (float*)d_out, n);
}